// Round 6
// baseline (628.670 us; speedup 1.0000x reference)
//
#include <hip/hip_runtime.h>
#include <hip/hip_fp16.h>
#include <math.h>

#define F_IN 128
#define D_OUT 64
#define LRELU 0.2f
#define BN_EPS 1e-3f

typedef __attribute__((ext_vector_type(8))) __bf16 bf16x8;
typedef __attribute__((ext_vector_type(4))) float f32x4;

// ---------------- BN statistics: per-column sum / sumsq ----------------
__global__ __launch_bounds__(256) void stats_kernel(const float* __restrict__ x,
                                                    float* __restrict__ sum,
                                                    float* __restrict__ sumsq,
                                                    int N, int rowsPerBlock) {
    int col  = threadIdx.x & 127;
    int half = threadIdx.x >> 7;
    int rbeg = blockIdx.x * rowsPerBlock;
    int rend = min(rbeg + rowsPerBlock, N);
    float s = 0.f, sq = 0.f;
    for (int r = rbeg + half; r < rend; r += 2) {
        float v = x[(size_t)r * F_IN + col];
        s += v; sq += v * v;
    }
    __shared__ float ls[256], lsq[256];
    ls[threadIdx.x] = s; lsq[threadIdx.x] = sq;
    __syncthreads();
    if (half == 0) {
        s  += ls[col + 128];
        sq += lsq[col + 128];
        atomicAdd(&sum[col], s);
        atomicAdd(&sumsq[col], sq);
    }
}

__global__ void finalize_stats(float* sum, float* sumsq, int N) {
    int c = threadIdx.x;  // 128 threads
    float mean = sum[c] / (float)N;
    float var  = sumsq[c] / (float)N - mean * mean;
    sum[c]   = mean;
    sumsq[c] = rsqrtf(var + BN_EPS);
}

// ---- prep: Bt_ext[c][0..383] = [Bh(k) | Bh(k) | Bl(k)] for c in [0,320) ----
// Split-bf16 3-term product folded into one K=384 GEMM:
//   Ah.Bh + Al.Bh + Ah.Bl  with A-sequence [Ah|Al|Ah].
__global__ __launch_bounds__(256) void prep_B(const float* __restrict__ K1,
                                              const float* __restrict__ K2,
                                              const float* __restrict__ W,
                                              __bf16* __restrict__ Bt) {
    int i = blockIdx.x * 256 + threadIdx.x;   // i = c*128 + k
    if (i >= 320 * 128) return;
    int c = i >> 7, k = i & 127;
    float v;
    if (c < 128)      v = K1[k * 128 + c];
    else if (c < 256) v = K2[k * 128 + (c - 128)];
    else              v = W[k * 64 + (c - 256)];
    __bf16 h = (__bf16)v;
    __bf16 l = (__bf16)(v - (float)h);
    size_t rb = (size_t)c * 384;
    Bt[rb + k]       = h;
    Bt[rb + 128 + k] = h;
    Bt[rb + 256 + k] = l;
}

// ---------------- xn = (x-mean)*rstd, split to bf16 hi/lo ----------------
__global__ __launch_bounds__(256) void xn_kernel(const float* __restrict__ x,
                                                 const float* __restrict__ meanv,
                                                 const float* __restrict__ rstdv,
                                                 __bf16* __restrict__ xnh,
                                                 __bf16* __restrict__ xnl,
                                                 int N, int Npad) {
    int idx = blockIdx.x * 256 + threadIdx.x;   // one 8-col group
    if (idx >= Npad * 16) return;
    int row = idx >> 4, g = (idx & 15) * 8;
    float f[8] = {0, 0, 0, 0, 0, 0, 0, 0};
    if (row < N) {
        float4 v0 = *(const float4*)&x[(size_t)row * F_IN + g];
        float4 v1 = *(const float4*)&x[(size_t)row * F_IN + g + 4];
        float4 m0 = *(const float4*)&meanv[g], m1 = *(const float4*)&meanv[g + 4];
        float4 r0 = *(const float4*)&rstdv[g], r1 = *(const float4*)&rstdv[g + 4];
        f[0] = (v0.x - m0.x) * r0.x; f[1] = (v0.y - m0.y) * r0.y;
        f[2] = (v0.z - m0.z) * r0.z; f[3] = (v0.w - m0.w) * r0.w;
        f[4] = (v1.x - m1.x) * r1.x; f[5] = (v1.y - m1.y) * r1.y;
        f[6] = (v1.z - m1.z) * r1.z; f[7] = (v1.w - m1.w) * r1.w;
    }
    bf16x8 hv, lv;
#pragma unroll
    for (int j = 0; j < 8; ++j) {
        __bf16 h = (__bf16)f[j];
        hv[j] = h;
        lv[j] = (__bf16)(f[j] - (float)h);
    }
    *(bf16x8*)&xnh[(size_t)row * F_IN + g] = hv;
    *(bf16x8*)&xnl[(size_t)row * F_IN + g] = lv;
}

// ---------------- GEMM: C = A_ext(Npad x 384) . Bt_ext^T (384 x 320) ----------------
// cols 0-127 -> a1 partials, 128-255 -> a2, 256-319 -> mapped (fp16).
// Live state kept small (3 acc chains, A in 32 regs, no LDS) to avoid the
// round-4/5 spill disaster (399/75 MB scratch writes).
__global__ __launch_bounds__(256) void gemm_kernel(const __bf16* __restrict__ xnh,
                                                   const __bf16* __restrict__ xnl,
                                                   const __bf16* __restrict__ Bt,
                                                   float* __restrict__ a1,
                                                   float* __restrict__ a2,
                                                   __half* __restrict__ mapped,
                                                   int N) {
    int tid   = threadIdx.x;
    int lane  = tid & 63;
    int w     = tid >> 6;
    int col16 = lane & 15;
    int quad  = lane >> 4;
    int base  = blockIdx.x * 64;
    int arow  = base + w * 16 + col16;   // pad rows are zero-filled: no guard

    const __bf16* ah = xnh + (size_t)arow * F_IN + quad * 8;
    const __bf16* al = xnl + (size_t)arow * F_IN + quad * 8;
    bf16x8 Ah[4], Al[4];
#pragma unroll
    for (int ks = 0; ks < 4; ++ks) {
        Ah[ks] = *(const bf16x8*)(ah + ks * 32);
        Al[ks] = *(const bf16x8*)(al + ks * 32);
    }

    float pa1[4] = {0, 0, 0, 0}, pa2[4] = {0, 0, 0, 0};

    for (int ct = 0; ct < 20; ++ct) {
        const __bf16* bp = Bt + (size_t)(ct * 16 + col16) * 384 + quad * 8;
        f32x4 c0 = {0, 0, 0, 0}, c1 = {0, 0, 0, 0}, c2 = {0, 0, 0, 0};
#pragma unroll
        for (int s = 0; s < 12; ++s) {
            bf16x8 Bv = *(const bf16x8*)(bp + s * 32);
            bf16x8 Av = (s < 4) ? Ah[s] : (s < 8) ? Al[s - 4] : Ah[s - 8];
            if (s % 3 == 0)      c0 = __builtin_amdgcn_mfma_f32_16x16x32_bf16(Av, Bv, c0, 0, 0, 0);
            else if (s % 3 == 1) c1 = __builtin_amdgcn_mfma_f32_16x16x32_bf16(Av, Bv, c1, 0, 0, 0);
            else                 c2 = __builtin_amdgcn_mfma_f32_16x16x32_bf16(Av, Bv, c2, 0, 0, 0);
        }
        f32x4 acc = c0 + c1 + c2;
        if (ct < 16) {
            // quadratic-form partial: dot C-tile with xn (reconstructed hi+lo)
            int cg = (ct & 7) * 16 + col16;
            bool isK1 = ct < 8;
#pragma unroll
            for (int reg = 0; reg < 4; ++reg) {
                int r = base + w * 16 + quad * 4 + reg;
                float xv = (float)xnh[(size_t)r * F_IN + cg] +
                           (float)xnl[(size_t)r * F_IN + cg];
                if (isK1) pa1[reg] += acc[reg] * xv;
                else      pa2[reg] += acc[reg] * xv;
            }
        } else {
#pragma unroll
            for (int reg = 0; reg < 4; ++reg) {
                int node = base + w * 16 + quad * 4 + reg;
                if (node < N)
                    mapped[(size_t)node * 64 + (ct - 16) * 16 + col16] =
                        __float2half(acc[reg]);
            }
        }
    }

    // reduce a1/a2 partials across the 16 col lanes of each quad
#pragma unroll
    for (int off = 1; off < 16; off <<= 1) {
#pragma unroll
        for (int reg = 0; reg < 4; ++reg) {
            pa1[reg] += __shfl_xor(pa1[reg], off, 64);
            pa2[reg] += __shfl_xor(pa2[reg], off, 64);
        }
    }
    if (col16 == 0) {
#pragma unroll
        for (int reg = 0; reg < 4; ++reg) {
            int node = base + w * 16 + quad * 4 + reg;
            if (node < N) {
                a1[node] = tanhf(pa1[reg]);
                a2[node] = tanhf(pa2[reg]);
            }
        }
    }
}

// ---------------- degree histogram ----------------
__global__ __launch_bounds__(256) void deg_kernel(const int* __restrict__ src,
                                                  int* __restrict__ deg, int E) {
    int e = blockIdx.x * 256 + threadIdx.x;
    if (e < E) atomicAdd(&deg[src[e]], 1);
}

// ---------------- exclusive scan of deg -> rowptr ----------------
__global__ __launch_bounds__(256) void scan1(const int* __restrict__ deg,
                                             int* __restrict__ pos,
                                             int* __restrict__ bsums, int N) {
    __shared__ int s[256];
    int i = blockIdx.x * 256 + threadIdx.x;
    int v = (i < N) ? deg[i] : 0;
    s[threadIdx.x] = v;
    for (int off = 1; off < 256; off <<= 1) {
        __syncthreads();
        int t = (threadIdx.x >= off) ? s[threadIdx.x - off] : 0;
        __syncthreads();
        s[threadIdx.x] += t;
    }
    __syncthreads();
    if (i < N) pos[i] = s[threadIdx.x];
    if (threadIdx.x == 255) bsums[blockIdx.x] = s[255];
}

__global__ __launch_bounds__(512) void scan2(int* bsums, int nb) {
    __shared__ int s[512];
    int v = (threadIdx.x < nb) ? bsums[threadIdx.x] : 0;
    s[threadIdx.x] = v;
    for (int off = 1; off < 512; off <<= 1) {
        __syncthreads();
        int t = (threadIdx.x >= off) ? s[threadIdx.x - off] : 0;
        __syncthreads();
        s[threadIdx.x] += t;
    }
    __syncthreads();
    if (threadIdx.x < nb) bsums[threadIdx.x] = s[threadIdx.x] - v;
}

__global__ __launch_bounds__(256) void scan3(const int* __restrict__ deg,
                                             int* __restrict__ pos,
                                             const int* __restrict__ bsums,
                                             int* __restrict__ rowptr, int N, int E) {
    int i = blockIdx.x * 256 + threadIdx.x;
    if (i < N) {
        int excl = pos[i] - deg[i] + bsums[blockIdx.x];
        rowptr[i] = excl;
        pos[i] = excl;
    }
    if (i == 0) rowptr[N] = E;
}

// ---------------- fused: edge score + counting-sort scatter ----------------
__global__ __launch_bounds__(256) void scatter_kernel(const int* __restrict__ src,
                                                      const int* __restrict__ dst,
                                                      const float* __restrict__ adj,
                                                      const float* __restrict__ a1,
                                                      const float* __restrict__ a2,
                                                      int* __restrict__ pos,
                                                      int2* __restrict__ sorted,
                                                      int E) {
    int e = blockIdx.x * 256 + threadIdx.x;
    if (e >= E) return;
    int s = src[e], d = dst[e];
    float v = adj[e] * (a1[s] + a2[d]);
    v = (v > 0.f) ? v : LRELU * v;
    float ex = __expf(v);   // max-shift skipped: identical math, e bounded
    int p = atomicAdd(&pos[s], 1);
    sorted[p] = make_int2(d, __float_as_int(ex));
}

// ---------------- SpMM (fp16 gather) + inline softmax denom + tanh ----------------
__global__ __launch_bounds__(256) void spmm_kernel(const int* __restrict__ rowptr,
                                                   const int2* __restrict__ sorted,
                                                   const __half2* __restrict__ mapped,
                                                   float* __restrict__ out, int N) {
    int w    = threadIdx.x >> 6;
    int lane = threadIdx.x & 63;
    int node = blockIdx.x * 4 + w;
    if (node >= N) return;
    int ep = lane >> 5;       // edge parity
    int c2 = lane & 31;       // half2 column pair
    int beg = rowptr[node], end = rowptr[node + 1];
    float ax = 0.f, ay = 0.f, accw = 0.f;
    for (int e = beg + ep; e < end; e += 2) {
        int2 pe  = sorted[e];
        float wg = __int_as_float(pe.y);
        float2 m = __half22float2(mapped[(size_t)pe.x * 32 + c2]);
        accw += wg;
        ax += wg * m.x;
        ay += wg * m.y;
    }
    ax   += __shfl_xor(ax, 32, 64);
    ay   += __shfl_xor(ay, 32, 64);
    accw += __shfl_xor(accw, 32, 64);
    if (lane < 32) {
        float inv = (accw != 0.f) ? 1.f / accw : 0.f;
        float2 o = make_float2(tanhf(ax * inv), tanhf(ay * inv));
        *(float2*)&out[(size_t)node * 64 + c2 * 2] = o;
    }
}

extern "C" void kernel_launch(void* const* d_in, const int* in_sizes, int n_in,
                              void* d_out, int out_size, void* d_ws, size_t ws_size,
                              hipStream_t stream) {
    const float* x   = (const float*)d_in[0];
    const int*   src = (const int*)d_in[1];
    const int*   dst = (const int*)d_in[2];
    const float* adj = (const float*)d_in[3];
    const float* W   = (const float*)d_in[4];
    const float* K1  = (const float*)d_in[5];
    const float* K2  = (const float*)d_in[6];
    float* out = (float*)d_out;

    const int N = in_sizes[0] / F_IN;
    const int E = in_sizes[1];
    const int Npad = (N + 63) & ~63;

    // workspace layout
    float* meanv  = (float*)d_ws;                 // 128
    float* rstdv  = meanv + 128;                  // 128
    int*   deg    = (int*)(rstdv + 128);          // N (contiguous with stats: one memset)
    float* a1     = (float*)(deg + N);            // N
    float* a2     = a1 + N;                       // N
    __half* mapped = (__half*)(a2 + N);           // N*64 fp16
    int*   rowptr = (int*)(mapped + (size_t)N * 64); // N+1
    int*   pos    = rowptr + (N + 1);             // N
    int*   bsums  = pos + N;                      // 1024
    uintptr_t sp  = ((uintptr_t)(bsums + 1024) + 15) & ~(uintptr_t)15;
    __bf16* xnh   = (__bf16*)sp;                  // Npad*128
    __bf16* xnl   = xnh + (size_t)Npad * F_IN;    // Npad*128
    __bf16* Bt    = xnl + (size_t)Npad * F_IN;    // 320*384
    int2*  sorted = (int2*)xnh;                   // E, ALIASES xnh (dead after gemm)

    // zero stats sums + deg
    hipMemsetAsync(d_ws, 0, (size_t)(256 + N) * sizeof(float), stream);

    deg_kernel<<<(E + 255) / 256, 256, 0, stream>>>(src, deg, E);

    int rpb = (N + 511) / 512;
    stats_kernel<<<512, 256, 0, stream>>>(x, meanv, rstdv, N, rpb);
    finalize_stats<<<1, 128, 0, stream>>>(meanv, rstdv, N);

    prep_B<<<(320 * 128 + 255) / 256, 256, 0, stream>>>(K1, K2, W, Bt);

    xn_kernel<<<(Npad * 16 + 255) / 256, 256, 0, stream>>>(x, meanv, rstdv,
                                                           xnh, xnl, N, Npad);

    gemm_kernel<<<Npad / 64, 256, 0, stream>>>(xnh, xnl, Bt, a1, a2, mapped, N);

    int nb1 = (N + 255) / 256;
    scan1<<<nb1, 256, 0, stream>>>(deg, pos, bsums, N);
    scan2<<<1, 512, 0, stream>>>(bsums, nb1);
    scan3<<<nb1, 256, 0, stream>>>(deg, pos, bsums, rowptr, N, E);

    scatter_kernel<<<(E + 255) / 256, 256, 0, stream>>>(src, dst, adj, a1, a2,
                                                        pos, sorted, E);

    spmm_kernel<<<(N + 3) / 4, 256, 0, stream>>>(rowptr, sorted,
                                                 (const __half2*)mapped, out, N);
}

// Round 7
// 609.071 us; speedup vs baseline: 1.0322x; 1.0322x over previous
//
#include <hip/hip_runtime.h>
#include <hip/hip_fp16.h>
#include <math.h>

#define F_IN 128
#define D_OUT 64
#define LRELU 0.2f
#define BN_EPS 1e-3f
#define TILE_HALVES 6144   // one 16-col B tile in fragment order: 12 steps * 64 lanes * 8 halves

typedef __attribute__((ext_vector_type(8))) __bf16 bf16x8;
typedef __attribute__((ext_vector_type(4))) float f32x4;

// ---------------- BN statistics: per-column sum / sumsq ----------------
__global__ __launch_bounds__(256) void stats_kernel(const float* __restrict__ x,
                                                    float* __restrict__ sum,
                                                    float* __restrict__ sumsq,
                                                    int N, int rowsPerBlock) {
    int col  = threadIdx.x & 127;
    int half = threadIdx.x >> 7;
    int rbeg = blockIdx.x * rowsPerBlock;
    int rend = min(rbeg + rowsPerBlock, N);
    float s = 0.f, sq = 0.f;
    for (int r = rbeg + half; r < rend; r += 2) {
        float v = x[(size_t)r * F_IN + col];
        s += v; sq += v * v;
    }
    __shared__ float ls[256], lsq[256];
    ls[threadIdx.x] = s; lsq[threadIdx.x] = sq;
    __syncthreads();
    if (half == 0) {
        s  += ls[col + 128];
        sq += lsq[col + 128];
        atomicAdd(&sum[col], s);
        atomicAdd(&sumsq[col], sq);
    }
}

__global__ void finalize_stats(float* sum, float* sumsq, int N) {
    int c = threadIdx.x;  // 128 threads
    float mean = sum[c] / (float)N;
    float var  = sumsq[c] / (float)N - mean * mean;
    sum[c]   = mean;
    sumsq[c] = rsqrtf(var + BN_EPS);
}

// ---- prep: B_ext (K=384: [Bh|Bh|Bl]) permuted into per-tile MFMA fragment order ----
// Btp[ct][(s*64 + lane)*8 + j] = B_ext[c = ct*16 + (lane&15)][p = s*32 + (lane>>4)*8 + j]
// so gemm's LDS reads are lane-contiguous 16B (conflict-free) and staging is a flat copy.
__global__ __launch_bounds__(256) void prep_B(const float* __restrict__ K1,
                                              const float* __restrict__ K2,
                                              const float* __restrict__ W,
                                              __bf16* __restrict__ Btp) {
    int i = blockIdx.x * 256 + threadIdx.x;   // i = c*128 + k
    if (i >= 320 * 128) return;
    int c = i >> 7, k = i & 127;
    float v;
    if (c < 128)      v = K1[k * 128 + c];
    else if (c < 256) v = K2[k * 128 + (c - 128)];
    else              v = W[k * 64 + (c - 256)];
    __bf16 h = (__bf16)v;
    __bf16 l = (__bf16)(v - (float)h);
    int ct = c >> 4, col16 = c & 15;
    size_t tb = (size_t)ct * TILE_HALVES;
#pragma unroll
    for (int t = 0; t < 3; ++t) {
        int p = k + t * 128;
        int s = p >> 5, quad = (p & 31) >> 3, j = p & 7;
        Btp[tb + (size_t)((s * 64 + quad * 16 + col16) * 8 + j)] = (t < 2) ? h : l;
    }
}

// ---------------- xn = (x-mean)*rstd, split to bf16 hi/lo ----------------
__global__ __launch_bounds__(256) void xn_kernel(const float* __restrict__ x,
                                                 const float* __restrict__ meanv,
                                                 const float* __restrict__ rstdv,
                                                 __bf16* __restrict__ xnh,
                                                 __bf16* __restrict__ xnl,
                                                 int N, int Npad) {
    int idx = blockIdx.x * 256 + threadIdx.x;   // one 8-col group
    if (idx >= Npad * 16) return;
    int row = idx >> 4, g = (idx & 15) * 8;
    float f[8] = {0, 0, 0, 0, 0, 0, 0, 0};
    if (row < N) {
        float4 v0 = *(const float4*)&x[(size_t)row * F_IN + g];
        float4 v1 = *(const float4*)&x[(size_t)row * F_IN + g + 4];
        float4 m0 = *(const float4*)&meanv[g], m1 = *(const float4*)&meanv[g + 4];
        float4 r0 = *(const float4*)&rstdv[g], r1 = *(const float4*)&rstdv[g + 4];
        f[0] = (v0.x - m0.x) * r0.x; f[1] = (v0.y - m0.y) * r0.y;
        f[2] = (v0.z - m0.z) * r0.z; f[3] = (v0.w - m0.w) * r0.w;
        f[4] = (v1.x - m1.x) * r1.x; f[5] = (v1.y - m1.y) * r1.y;
        f[6] = (v1.z - m1.z) * r1.z; f[7] = (v1.w - m1.w) * r1.w;
    }
    bf16x8 hv, lv;
#pragma unroll
    for (int j = 0; j < 8; ++j) {
        __bf16 h = (__bf16)f[j];
        hv[j] = h;
        lv[j] = (__bf16)(f[j] - (float)h);
    }
    *(bf16x8*)&xnh[(size_t)row * F_IN + g] = hv;
    *(bf16x8*)&xnl[(size_t)row * F_IN + g] = lv;
}

// ---------------- GEMM with LDS double-buffered B tiles ----------------
// C = A_ext(Npad x 384) . B_ext^T; cols 0-127 -> a1 dots, 128-255 -> a2,
// 256-319 -> mapped (fp16). B staged through LDS in fragment order:
// per-lane global B loads (r6: 236 VGPR, 1 wave/SIMD, 220us) are replaced by
// cooperative 12KB tile staging + conflict-free ds_read_b128.
__global__ __launch_bounds__(256, 2) void gemm_kernel(const __bf16* __restrict__ xnh,
                                                      const __bf16* __restrict__ xnl,
                                                      const __bf16* __restrict__ Btp,
                                                      float* __restrict__ a1,
                                                      float* __restrict__ a2,
                                                      __half* __restrict__ mapped,
                                                      int N) {
    __shared__ __bf16 Bs[2][TILE_HALVES];   // 2 x 12 KB
    int tid   = threadIdx.x;
    int lane  = tid & 63;
    int w     = tid >> 6;
    int col16 = lane & 15;
    int quad  = lane >> 4;
    int base  = blockIdx.x * 64;
    int arow  = base + w * 16 + col16;   // pad rows zero-filled: no guard

    const __bf16* ah = xnh + (size_t)arow * F_IN + quad * 8;
    const __bf16* al = xnl + (size_t)arow * F_IN + quad * 8;
    bf16x8 Ah[4], Al[4];
#pragma unroll
    for (int ks = 0; ks < 4; ++ks) {
        Ah[ks] = *(const bf16x8*)(ah + ks * 32);
        Al[ks] = *(const bf16x8*)(al + ks * 32);
    }

    // prologue: stage tile 0
    {
        const float4* g = (const float4*)Btp;
        float4 s0 = g[tid], s1 = g[tid + 256], s2 = g[tid + 512];
        *(float4*)&Bs[0][(size_t)tid * 8]        = s0;
        *(float4*)&Bs[0][(size_t)tid * 8 + 2048] = s1;
        *(float4*)&Bs[0][(size_t)tid * 8 + 4096] = s2;
    }
    __syncthreads();

    float pa1[4] = {0, 0, 0, 0}, pa2[4] = {0, 0, 0, 0};

    for (int ct = 0; ct < 20; ++ct) {
        int cur = ct & 1;
        // issue next tile's global loads (latency covered by this tile's compute)
        float4 s0, s1, s2;
        if (ct + 1 < 20) {
            const float4* g = (const float4*)(Btp + (size_t)(ct + 1) * TILE_HALVES);
            s0 = g[tid]; s1 = g[tid + 256]; s2 = g[tid + 512];
        }

        f32x4 c0 = {0, 0, 0, 0}, c1 = {0, 0, 0, 0}, c2 = {0, 0, 0, 0};
#pragma unroll
        for (int s = 0; s < 12; ++s) {
            bf16x8 Bv = *(const bf16x8*)&Bs[cur][(size_t)((s * 64 + lane) * 8)];
            bf16x8 Av = (s < 4) ? Ah[s] : (s < 8) ? Al[s - 4] : Ah[s - 8];
            if (s % 3 == 0)      c0 = __builtin_amdgcn_mfma_f32_16x16x32_bf16(Av, Bv, c0, 0, 0, 0);
            else if (s % 3 == 1) c1 = __builtin_amdgcn_mfma_f32_16x16x32_bf16(Av, Bv, c1, 0, 0, 0);
            else                 c2 = __builtin_amdgcn_mfma_f32_16x16x32_bf16(Av, Bv, c2, 0, 0, 0);
        }
        f32x4 acc = c0 + c1 + c2;

        if (ct < 16) {
            // quadratic-form partial: dot C-tile with xn (hi+lo, L1-resident)
            int cg = (ct & 7) * 16 + col16;
            bool isK1 = ct < 8;
#pragma unroll
            for (int reg = 0; reg < 4; ++reg) {
                int r = base + w * 16 + quad * 4 + reg;
                float xv = (float)xnh[(size_t)r * F_IN + cg] +
                           (float)xnl[(size_t)r * F_IN + cg];
                if (isK1) pa1[reg] += acc[reg] * xv;
                else      pa2[reg] += acc[reg] * xv;
            }
        } else {
#pragma unroll
            for (int reg = 0; reg < 4; ++reg) {
                int node = base + w * 16 + quad * 4 + reg;
                if (node < N)
                    mapped[(size_t)node * 64 + (ct - 16) * 16 + col16] =
                        __float2half(acc[reg]);
            }
        }

        // write next tile into the other buffer (its readers finished at the
        // barrier that ended iteration ct-1), then one barrier to publish.
        if (ct + 1 < 20) {
            int nxt = cur ^ 1;
            *(float4*)&Bs[nxt][(size_t)tid * 8]        = s0;
            *(float4*)&Bs[nxt][(size_t)tid * 8 + 2048] = s1;
            *(float4*)&Bs[nxt][(size_t)tid * 8 + 4096] = s2;
            __syncthreads();
        }
    }

    // reduce a1/a2 partials across the 16 col lanes of each quad
#pragma unroll
    for (int off = 1; off < 16; off <<= 1) {
#pragma unroll
        for (int reg = 0; reg < 4; ++reg) {
            pa1[reg] += __shfl_xor(pa1[reg], off, 64);
            pa2[reg] += __shfl_xor(pa2[reg], off, 64);
        }
    }
    if (col16 == 0) {
#pragma unroll
        for (int reg = 0; reg < 4; ++reg) {
            int node = base + w * 16 + quad * 4 + reg;
            if (node < N) {
                a1[node] = tanhf(pa1[reg]);
                a2[node] = tanhf(pa2[reg]);
            }
        }
    }
}

// ---------------- degree histogram ----------------
__global__ __launch_bounds__(256) void deg_kernel(const int* __restrict__ src,
                                                  int* __restrict__ deg, int E) {
    int e = blockIdx.x * 256 + threadIdx.x;
    if (e < E) atomicAdd(&deg[src[e]], 1);
}

// ---------------- exclusive scan of deg -> rowptr ----------------
__global__ __launch_bounds__(256) void scan1(const int* __restrict__ deg,
                                             int* __restrict__ pos,
                                             int* __restrict__ bsums, int N) {
    __shared__ int s[256];
    int i = blockIdx.x * 256 + threadIdx.x;
    int v = (i < N) ? deg[i] : 0;
    s[threadIdx.x] = v;
    for (int off = 1; off < 256; off <<= 1) {
        __syncthreads();
        int t = (threadIdx.x >= off) ? s[threadIdx.x - off] : 0;
        __syncthreads();
        s[threadIdx.x] += t;
    }
    __syncthreads();
    if (i < N) pos[i] = s[threadIdx.x];
    if (threadIdx.x == 255) bsums[blockIdx.x] = s[255];
}

__global__ __launch_bounds__(512) void scan2(int* bsums, int nb) {
    __shared__ int s[512];
    int v = (threadIdx.x < nb) ? bsums[threadIdx.x] : 0;
    s[threadIdx.x] = v;
    for (int off = 1; off < 512; off <<= 1) {
        __syncthreads();
        int t = (threadIdx.x >= off) ? s[threadIdx.x - off] : 0;
        __syncthreads();
        s[threadIdx.x] += t;
    }
    __syncthreads();
    if (threadIdx.x < nb) bsums[threadIdx.x] = s[threadIdx.x] - v;
}

__global__ __launch_bounds__(256) void scan3(const int* __restrict__ deg,
                                             int* __restrict__ pos,
                                             const int* __restrict__ bsums,
                                             int* __restrict__ rowptr, int N, int E) {
    int i = blockIdx.x * 256 + threadIdx.x;
    if (i < N) {
        int excl = pos[i] - deg[i] + bsums[blockIdx.x];
        rowptr[i] = excl;
        pos[i] = excl;
    }
    if (i == 0) rowptr[N] = E;
}

// ---------------- fused: edge score + counting-sort scatter ----------------
__global__ __launch_bounds__(256) void scatter_kernel(const int* __restrict__ src,
                                                      const int* __restrict__ dst,
                                                      const float* __restrict__ adj,
                                                      const float* __restrict__ a1,
                                                      const float* __restrict__ a2,
                                                      int* __restrict__ pos,
                                                      int2* __restrict__ sorted,
                                                      int E) {
    int e = blockIdx.x * 256 + threadIdx.x;
    if (e >= E) return;
    int s = src[e], d = dst[e];
    float v = adj[e] * (a1[s] + a2[d]);
    v = (v > 0.f) ? v : LRELU * v;
    float ex = __expf(v);   // max-shift skipped: identical math, e bounded
    int p = atomicAdd(&pos[s], 1);
    sorted[p] = make_int2(d, __float_as_int(ex));
}

// ---------------- SpMM (fp16 gather) + inline softmax denom + tanh ----------------
__global__ __launch_bounds__(256) void spmm_kernel(const int* __restrict__ rowptr,
                                                   const int2* __restrict__ sorted,
                                                   const __half2* __restrict__ mapped,
                                                   float* __restrict__ out, int N) {
    int w    = threadIdx.x >> 6;
    int lane = threadIdx.x & 63;
    int node = blockIdx.x * 4 + w;
    if (node >= N) return;
    int ep = lane >> 5;       // edge parity
    int c2 = lane & 31;       // half2 column pair
    int beg = rowptr[node], end = rowptr[node + 1];
    float ax = 0.f, ay = 0.f, accw = 0.f;
    for (int e = beg + ep; e < end; e += 2) {
        int2 pe  = sorted[e];
        float wg = __int_as_float(pe.y);
        float2 m = __half22float2(mapped[(size_t)pe.x * 32 + c2]);
        accw += wg;
        ax += wg * m.x;
        ay += wg * m.y;
    }
    ax   += __shfl_xor(ax, 32, 64);
    ay   += __shfl_xor(ay, 32, 64);
    accw += __shfl_xor(accw, 32, 64);
    if (lane < 32) {
        float inv = (accw != 0.f) ? 1.f / accw : 0.f;
        float2 o = make_float2(tanhf(ax * inv), tanhf(ay * inv));
        *(float2*)&out[(size_t)node * 64 + c2 * 2] = o;
    }
}

extern "C" void kernel_launch(void* const* d_in, const int* in_sizes, int n_in,
                              void* d_out, int out_size, void* d_ws, size_t ws_size,
                              hipStream_t stream) {
    const float* x   = (const float*)d_in[0];
    const int*   src = (const int*)d_in[1];
    const int*   dst = (const int*)d_in[2];
    const float* adj = (const float*)d_in[3];
    const float* W   = (const float*)d_in[4];
    const float* K1  = (const float*)d_in[5];
    const float* K2  = (const float*)d_in[6];
    float* out = (float*)d_out;

    const int N = in_sizes[0] / F_IN;
    const int E = in_sizes[1];
    const int Npad = (N + 63) & ~63;

    // workspace layout
    float* meanv  = (float*)d_ws;                 // 128
    float* rstdv  = meanv + 128;                  // 128
    int*   deg    = (int*)(rstdv + 128);          // N (contiguous with stats: one memset)
    float* a1     = (float*)(deg + N);            // N
    float* a2     = a1 + N;                       // N
    __half* mapped = (__half*)(a2 + N);           // N*64 fp16
    int*   rowptr = (int*)(mapped + (size_t)N * 64); // N+1
    int*   pos    = rowptr + (N + 1);             // N
    int*   bsums  = pos + N;                      // 1024
    uintptr_t sp  = ((uintptr_t)(bsums + 1024) + 15) & ~(uintptr_t)15;
    __bf16* xnh   = (__bf16*)sp;                  // Npad*128
    __bf16* xnl   = xnh + (size_t)Npad * F_IN;    // Npad*128
    __bf16* Btp   = xnl + (size_t)Npad * F_IN;    // 20*6144 = 320*384
    int2*  sorted = (int2*)xnh;                   // E, ALIASES xnh (dead after gemm)

    // zero stats sums + deg
    hipMemsetAsync(d_ws, 0, (size_t)(256 + N) * sizeof(float), stream);

    deg_kernel<<<(E + 255) / 256, 256, 0, stream>>>(src, deg, E);

    int rpb = (N + 511) / 512;
    stats_kernel<<<512, 256, 0, stream>>>(x, meanv, rstdv, N, rpb);
    finalize_stats<<<1, 128, 0, stream>>>(meanv, rstdv, N);

    prep_B<<<(320 * 128 + 255) / 256, 256, 0, stream>>>(K1, K2, W, Btp);

    xn_kernel<<<(Npad * 16 + 255) / 256, 256, 0, stream>>>(x, meanv, rstdv,
                                                           xnh, xnl, N, Npad);

    gemm_kernel<<<Npad / 64, 256, 0, stream>>>(xnh, xnl, Btp, a1, a2, mapped, N);

    int nb1 = (N + 255) / 256;
    scan1<<<nb1, 256, 0, stream>>>(deg, pos, bsums, N);
    scan2<<<1, 512, 0, stream>>>(bsums, nb1);
    scan3<<<nb1, 256, 0, stream>>>(deg, pos, bsums, rowptr, N, E);

    scatter_kernel<<<(E + 255) / 256, 256, 0, stream>>>(src, dst, adj, a1, a2,
                                                        pos, sorted, E);

    spmm_kernel<<<(N + 3) / 4, 256, 0, stream>>>(rowptr, sorted,
                                                 (const __half2*)mapped, out, N);
}

// Round 8
// 593.969 us; speedup vs baseline: 1.0584x; 1.0254x over previous
//
#include <hip/hip_runtime.h>
#include <hip/hip_fp16.h>
#include <math.h>

#define F_IN 128
#define D_OUT 64
#define LRELU 0.2f
#define BN_EPS 1e-3f
#define TILE_HALVES 6144   // one 16-col B tile in fragment order: 12 steps * 64 lanes * 8 halves

typedef __attribute__((ext_vector_type(8))) __bf16 bf16x8;
typedef __attribute__((ext_vector_type(4))) float f32x4;

// ---------------- BN statistics: per-column sum / sumsq ----------------
__global__ __launch_bounds__(256) void stats_kernel(const float* __restrict__ x,
                                                    float* __restrict__ sum,
                                                    float* __restrict__ sumsq,
                                                    int N, int rowsPerBlock) {
    int col  = threadIdx.x & 127;
    int half = threadIdx.x >> 7;
    int rbeg = blockIdx.x * rowsPerBlock;
    int rend = min(rbeg + rowsPerBlock, N);
    float s = 0.f, sq = 0.f;
    for (int r = rbeg + half; r < rend; r += 2) {
        float v = x[(size_t)r * F_IN + col];
        s += v; sq += v * v;
    }
    __shared__ float ls[256], lsq[256];
    ls[threadIdx.x] = s; lsq[threadIdx.x] = sq;
    __syncthreads();
    if (half == 0) {
        s  += ls[col + 128];
        sq += lsq[col + 128];
        atomicAdd(&sum[col], s);
        atomicAdd(&sumsq[col], sq);
    }
}

__global__ void finalize_stats(float* sum, float* sumsq, int N) {
    int c = threadIdx.x;  // 128 threads
    float mean = sum[c] / (float)N;
    float var  = sumsq[c] / (float)N - mean * mean;
    sum[c]   = mean;
    sumsq[c] = rsqrtf(var + BN_EPS);
}

// ---- prep: B_ext (K=384: [Bh|Bh|Bl]) permuted into per-tile MFMA fragment order ----
// Btp[ct][(s*64 + lane)*8 + j] = B_ext[c = ct*16 + (lane&15)][p = s*32 + (lane>>4)*8 + j]
// Flat order == the order gemm's waves consume it, so both the LDS DMA
// (wave-uniform base + lane*16) and ds_read_b128 are identity-mapped.
__global__ __launch_bounds__(256) void prep_B(const float* __restrict__ K1,
                                              const float* __restrict__ K2,
                                              const float* __restrict__ W,
                                              __bf16* __restrict__ Btp) {
    int i = blockIdx.x * 256 + threadIdx.x;   // i = c*128 + k
    if (i >= 320 * 128) return;
    int c = i >> 7, k = i & 127;
    float v;
    if (c < 128)      v = K1[k * 128 + c];
    else if (c < 256) v = K2[k * 128 + (c - 128)];
    else              v = W[k * 64 + (c - 256)];
    __bf16 h = (__bf16)v;
    __bf16 l = (__bf16)(v - (float)h);
    int ct = c >> 4, col16 = c & 15;
    size_t tb = (size_t)ct * TILE_HALVES;
#pragma unroll
    for (int t = 0; t < 3; ++t) {
        int p = k + t * 128;
        int s = p >> 5, quad = (p & 31) >> 3, j = p & 7;
        Btp[tb + (size_t)((s * 64 + quad * 16 + col16) * 8 + j)] = (t < 2) ? h : l;
    }
}

// ---------------- xn = (x-mean)*rstd, split to bf16 hi/lo ----------------
__global__ __launch_bounds__(256) void xn_kernel(const float* __restrict__ x,
                                                 const float* __restrict__ meanv,
                                                 const float* __restrict__ rstdv,
                                                 __bf16* __restrict__ xnh,
                                                 __bf16* __restrict__ xnl,
                                                 int N, int Npad) {
    int idx = blockIdx.x * 256 + threadIdx.x;   // one 8-col group
    if (idx >= Npad * 16) return;
    int row = idx >> 4, g = (idx & 15) * 8;
    float f[8] = {0, 0, 0, 0, 0, 0, 0, 0};
    if (row < N) {
        float4 v0 = *(const float4*)&x[(size_t)row * F_IN + g];
        float4 v1 = *(const float4*)&x[(size_t)row * F_IN + g + 4];
        float4 m0 = *(const float4*)&meanv[g], m1 = *(const float4*)&meanv[g + 4];
        float4 r0 = *(const float4*)&rstdv[g], r1 = *(const float4*)&rstdv[g + 4];
        f[0] = (v0.x - m0.x) * r0.x; f[1] = (v0.y - m0.y) * r0.y;
        f[2] = (v0.z - m0.z) * r0.z; f[3] = (v0.w - m0.w) * r0.w;
        f[4] = (v1.x - m1.x) * r1.x; f[5] = (v1.y - m1.y) * r1.y;
        f[6] = (v1.z - m1.z) * r1.z; f[7] = (v1.w - m1.w) * r1.w;
    }
    bf16x8 hv, lv;
#pragma unroll
    for (int j = 0; j < 8; ++j) {
        __bf16 h = (__bf16)f[j];
        hv[j] = h;
        lv[j] = (__bf16)(f[j] - (float)h);
    }
    *(bf16x8*)&xnh[(size_t)row * F_IN + g] = hv;
    *(bf16x8*)&xnl[(size_t)row * F_IN + g] = lv;
}

// ---------------- GEMM with async global->LDS double-buffered B tiles ----------------
// r7 held the prefetch tile in 12 VGPRs across the compute phase -> allocator
// spilled them every iteration (241 MB scratch writes). global_load_lds DMAs
// the tile straight to LDS: zero staging registers, __syncthreads drains vmcnt.
__global__ __launch_bounds__(256, 2) void gemm_kernel(const __bf16* __restrict__ xnh,
                                                      const __bf16* __restrict__ xnl,
                                                      const __bf16* __restrict__ Btp,
                                                      float* __restrict__ a1,
                                                      float* __restrict__ a2,
                                                      __half* __restrict__ mapped,
                                                      int N) {
    __shared__ __align__(16) __bf16 Bs[2][TILE_HALVES];   // 2 x 12 KB
    int tid   = threadIdx.x;
    int lane  = tid & 63;
    int w     = tid >> 6;
    int col16 = lane & 15;
    int quad  = lane >> 4;
    int base  = blockIdx.x * 64;
    int arow  = base + w * 16 + col16;   // pad rows zero-filled: no guard

    const __bf16* ah = xnh + (size_t)arow * F_IN + quad * 8;
    const __bf16* al = xnl + (size_t)arow * F_IN + quad * 8;
    bf16x8 Ah[4], Al[4];
#pragma unroll
    for (int ks = 0; ks < 4; ++ks) {
        Ah[ks] = *(const bf16x8*)(ah + ks * 32);
        Al[ks] = *(const bf16x8*)(al + ks * 32);
    }

    // wave w owns bytes [w*3072, (w+1)*3072) of each 12 KB tile:
    // 3 DMA calls x (64 lanes x 16 B); LDS dest = uniform base + lane*16.
    const __bf16* gsrc0 = Btp + w * 1536 + lane * 8;   // per-lane global addr
    // prologue: stage tile 0
#pragma unroll
    for (int j = 0; j < 3; ++j) {
        __builtin_amdgcn_global_load_lds(
            (const __attribute__((address_space(1))) void*)(gsrc0 + j * 512),
            (__attribute__((address_space(3))) void*)(&Bs[0][w * 1536 + j * 512]),
            16, 0, 0);
    }
    __syncthreads();

    float pa1[4] = {0, 0, 0, 0}, pa2[4] = {0, 0, 0, 0};

    for (int ct = 0; ct < 20; ++ct) {
        int cur = ct & 1;
        // async-stage next tile into the other buffer (its last readers passed
        // the barrier that ended iteration ct-1)
        if (ct + 1 < 20) {
            int nxt = cur ^ 1;
            const __bf16* g = gsrc0 + (size_t)(ct + 1) * TILE_HALVES;
#pragma unroll
            for (int j = 0; j < 3; ++j) {
                __builtin_amdgcn_global_load_lds(
                    (const __attribute__((address_space(1))) void*)(g + j * 512),
                    (__attribute__((address_space(3))) void*)(&Bs[nxt][w * 1536 + j * 512]),
                    16, 0, 0);
            }
        }

        f32x4 c0 = {0, 0, 0, 0}, c1 = {0, 0, 0, 0}, c2 = {0, 0, 0, 0};
#pragma unroll
        for (int s = 0; s < 12; ++s) {
            bf16x8 Bv = *(const bf16x8*)&Bs[cur][(size_t)((s * 64 + lane) * 8)];
            bf16x8 Av = (s < 4) ? Ah[s] : (s < 8) ? Al[s - 4] : Ah[s - 8];
            if (s % 3 == 0)      c0 = __builtin_amdgcn_mfma_f32_16x16x32_bf16(Av, Bv, c0, 0, 0, 0);
            else if (s % 3 == 1) c1 = __builtin_amdgcn_mfma_f32_16x16x32_bf16(Av, Bv, c1, 0, 0, 0);
            else                 c2 = __builtin_amdgcn_mfma_f32_16x16x32_bf16(Av, Bv, c2, 0, 0, 0);
        }
        f32x4 acc = c0 + c1 + c2;

        if (ct < 16) {
            // quadratic-form partial: dot C-tile with xn (hi+lo, L1-resident)
            int cg = (ct & 7) * 16 + col16;
            bool isK1 = ct < 8;
#pragma unroll
            for (int reg = 0; reg < 4; ++reg) {
                int r = base + w * 16 + quad * 4 + reg;
                float xv = (float)xnh[(size_t)r * F_IN + cg] +
                           (float)xnl[(size_t)r * F_IN + cg];
                if (isK1) pa1[reg] += acc[reg] * xv;
                else      pa2[reg] += acc[reg] * xv;
            }
        } else {
#pragma unroll
            for (int reg = 0; reg < 4; ++reg) {
                int node = base + w * 16 + quad * 4 + reg;
                if (node < N)
                    mapped[(size_t)node * 64 + (ct - 16) * 16 + col16] =
                        __float2half(acc[reg]);
            }
        }

        if (ct + 1 < 20) __syncthreads();   // drains DMA vmcnt, publishes next tile
    }

    // reduce a1/a2 partials across the 16 col lanes of each quad
#pragma unroll
    for (int off = 1; off < 16; off <<= 1) {
#pragma unroll
        for (int reg = 0; reg < 4; ++reg) {
            pa1[reg] += __shfl_xor(pa1[reg], off, 64);
            pa2[reg] += __shfl_xor(pa2[reg], off, 64);
        }
    }
    if (col16 == 0) {
#pragma unroll
        for (int reg = 0; reg < 4; ++reg) {
            int node = base + w * 16 + quad * 4 + reg;
            if (node < N) {
                a1[node] = tanhf(pa1[reg]);
                a2[node] = tanhf(pa2[reg]);
            }
        }
    }
}

// ---------------- degree histogram ----------------
__global__ __launch_bounds__(256) void deg_kernel(const int* __restrict__ src,
                                                  int* __restrict__ deg, int E) {
    int e = blockIdx.x * 256 + threadIdx.x;
    if (e < E) atomicAdd(&deg[src[e]], 1);
}

// ---------------- exclusive scan of deg -> rowptr ----------------
__global__ __launch_bounds__(256) void scan1(const int* __restrict__ deg,
                                             int* __restrict__ pos,
                                             int* __restrict__ bsums, int N) {
    __shared__ int s[256];
    int i = blockIdx.x * 256 + threadIdx.x;
    int v = (i < N) ? deg[i] : 0;
    s[threadIdx.x] = v;
    for (int off = 1; off < 256; off <<= 1) {
        __syncthreads();
        int t = (threadIdx.x >= off) ? s[threadIdx.x - off] : 0;
        __syncthreads();
        s[threadIdx.x] += t;
    }
    __syncthreads();
    if (i < N) pos[i] = s[threadIdx.x];
    if (threadIdx.x == 255) bsums[blockIdx.x] = s[255];
}

__global__ __launch_bounds__(512) void scan2(int* bsums, int nb) {
    __shared__ int s[512];
    int v = (threadIdx.x < nb) ? bsums[threadIdx.x] : 0;
    s[threadIdx.x] = v;
    for (int off = 1; off < 512; off <<= 1) {
        __syncthreads();
        int t = (threadIdx.x >= off) ? s[threadIdx.x - off] : 0;
        __syncthreads();
        s[threadIdx.x] += t;
    }
    __syncthreads();
    if (threadIdx.x < nb) bsums[threadIdx.x] = s[threadIdx.x] - v;
}

__global__ __launch_bounds__(256) void scan3(const int* __restrict__ deg,
                                             int* __restrict__ pos,
                                             const int* __restrict__ bsums,
                                             int* __restrict__ rowptr, int N, int E) {
    int i = blockIdx.x * 256 + threadIdx.x;
    if (i < N) {
        int excl = pos[i] - deg[i] + bsums[blockIdx.x];
        rowptr[i] = excl;
        pos[i] = excl;
    }
    if (i == 0) rowptr[N] = E;
}

// ---------------- fused: edge score + counting-sort scatter ----------------
__global__ __launch_bounds__(256) void scatter_kernel(const int* __restrict__ src,
                                                      const int* __restrict__ dst,
                                                      const float* __restrict__ adj,
                                                      const float* __restrict__ a1,
                                                      const float* __restrict__ a2,
                                                      int* __restrict__ pos,
                                                      int2* __restrict__ sorted,
                                                      int E) {
    int e = blockIdx.x * 256 + threadIdx.x;
    if (e >= E) return;
    int s = src[e], d = dst[e];
    float v = adj[e] * (a1[s] + a2[d]);
    v = (v > 0.f) ? v : LRELU * v;
    float ex = __expf(v);   // max-shift skipped: identical math, e bounded
    int p = atomicAdd(&pos[s], 1);
    sorted[p] = make_int2(d, __float_as_int(ex));
}

// ---------------- SpMM (fp16 gather) + inline softmax denom + tanh ----------------
__global__ __launch_bounds__(256) void spmm_kernel(const int* __restrict__ rowptr,
                                                   const int2* __restrict__ sorted,
                                                   const __half2* __restrict__ mapped,
                                                   float* __restrict__ out, int N) {
    int w    = threadIdx.x >> 6;
    int lane = threadIdx.x & 63;
    int node = blockIdx.x * 4 + w;
    if (node >= N) return;
    int ep = lane >> 5;       // edge parity
    int c2 = lane & 31;       // half2 column pair
    int beg = rowptr[node], end = rowptr[node + 1];
    float ax = 0.f, ay = 0.f, accw = 0.f;
    for (int e = beg + ep; e < end; e += 2) {
        int2 pe  = sorted[e];
        float wg = __int_as_float(pe.y);
        float2 m = __half22float2(mapped[(size_t)pe.x * 32 + c2]);
        accw += wg;
        ax += wg * m.x;
        ay += wg * m.y;
    }
    ax   += __shfl_xor(ax, 32, 64);
    ay   += __shfl_xor(ay, 32, 64);
    accw += __shfl_xor(accw, 32, 64);
    if (lane < 32) {
        float inv = (accw != 0.f) ? 1.f / accw : 0.f;
        float2 o = make_float2(tanhf(ax * inv), tanhf(ay * inv));
        *(float2*)&out[(size_t)node * 64 + c2 * 2] = o;
    }
}

extern "C" void kernel_launch(void* const* d_in, const int* in_sizes, int n_in,
                              void* d_out, int out_size, void* d_ws, size_t ws_size,
                              hipStream_t stream) {
    const float* x   = (const float*)d_in[0];
    const int*   src = (const int*)d_in[1];
    const int*   dst = (const int*)d_in[2];
    const float* adj = (const float*)d_in[3];
    const float* W   = (const float*)d_in[4];
    const float* K1  = (const float*)d_in[5];
    const float* K2  = (const float*)d_in[6];
    float* out = (float*)d_out;

    const int N = in_sizes[0] / F_IN;
    const int E = in_sizes[1];
    const int Npad = (N + 63) & ~63;

    // workspace layout
    float* meanv  = (float*)d_ws;                 // 128
    float* rstdv  = meanv + 128;                  // 128
    int*   deg    = (int*)(rstdv + 128);          // N (contiguous with stats: one memset)
    float* a1     = (float*)(deg + N);            // N
    float* a2     = a1 + N;                       // N
    __half* mapped = (__half*)(a2 + N);           // N*64 fp16
    int*   rowptr = (int*)(mapped + (size_t)N * 64); // N+1
    int*   pos    = rowptr + (N + 1);             // N
    int*   bsums  = pos + N;                      // 1024
    uintptr_t sp  = ((uintptr_t)(bsums + 1024) + 15) & ~(uintptr_t)15;
    __bf16* xnh   = (__bf16*)sp;                  // Npad*128
    __bf16* xnl   = xnh + (size_t)Npad * F_IN;    // Npad*128
    __bf16* Btp   = xnl + (size_t)Npad * F_IN;    // 20*6144 = 320*384
    int2*  sorted = (int2*)xnh;                   // E, ALIASES xnh (dead after gemm)

    // zero stats sums + deg
    hipMemsetAsync(d_ws, 0, (size_t)(256 + N) * sizeof(float), stream);

    deg_kernel<<<(E + 255) / 256, 256, 0, stream>>>(src, deg, E);

    int rpb = (N + 511) / 512;
    stats_kernel<<<512, 256, 0, stream>>>(x, meanv, rstdv, N, rpb);
    finalize_stats<<<1, 128, 0, stream>>>(meanv, rstdv, N);

    prep_B<<<(320 * 128 + 255) / 256, 256, 0, stream>>>(K1, K2, W, Btp);

    xn_kernel<<<(Npad * 16 + 255) / 256, 256, 0, stream>>>(x, meanv, rstdv,
                                                           xnh, xnl, N, Npad);

    gemm_kernel<<<Npad / 64, 256, 0, stream>>>(xnh, xnl, Btp, a1, a2, mapped, N);

    int nb1 = (N + 255) / 256;
    scan1<<<nb1, 256, 0, stream>>>(deg, pos, bsums, N);
    scan2<<<1, 512, 0, stream>>>(bsums, nb1);
    scan3<<<nb1, 256, 0, stream>>>(deg, pos, bsums, rowptr, N, E);

    scatter_kernel<<<(E + 255) / 256, 256, 0, stream>>>(src, dst, adj, a1, a2,
                                                        pos, sorted, E);

    spmm_kernel<<<(N + 3) / 4, 256, 0, stream>>>(rowptr, sorted,
                                                 (const __half2*)mapped, out, N);
}